// Round 1
// baseline (1479.147 us; speedup 1.0000x reference)
//
#include <hip/hip_runtime.h>
#include <math.h>

#define NN 50000
#define EE 200000
#define DD 256
#define HH 8
#define DKK 32
#define NODES_PER_BLOCK 32

constexpr float RSQRT_DK = 0.17677669529663687f;  // 1/sqrt(32)

// ---------------------------------------------------------------------------
// SGEMM: C[nrows,256] = X[nrows,256] @ W[256,256] + bias
// optional epilogue: C = C*alpha + xres*(1-alpha), alpha = sigmoid(skip[0])
// 64x64 tile, BK=16, 256 threads, 4x4 micro-tile per thread.
// ---------------------------------------------------------------------------
__global__ void sgemm_kernel(const float* __restrict__ X, const float* __restrict__ W,
                             const float* __restrict__ bias, float* __restrict__ C,
                             int nrows, const float* __restrict__ xres,
                             const float* __restrict__ skip) {
    __shared__ __align__(16) float As[16][64];  // [k][m]
    __shared__ __align__(16) float Bs[16][64];  // [k][n]
    const int t = threadIdx.x;
    const int row0 = blockIdx.x * 64, col0 = blockIdx.y * 64;
    const int tr = t >> 4, tc = t & 15;
    float acc[4][4] = {};

    const int ra  = row0 + (t >> 2);   // A-load row
    const int kk4 = (t & 3) << 2;      // A-load k sub-offset

    for (int k0 = 0; k0 < 256; k0 += 16) {
        float4 a4 = make_float4(0.f, 0.f, 0.f, 0.f);
        if (ra < nrows) a4 = *(const float4*)&X[(size_t)ra * 256 + k0 + kk4];
        As[kk4 + 0][t >> 2] = a4.x;
        As[kk4 + 1][t >> 2] = a4.y;
        As[kk4 + 2][t >> 2] = a4.z;
        As[kk4 + 3][t >> 2] = a4.w;
        *(float4*)&Bs[t >> 4][(t & 15) << 2] =
            *(const float4*)&W[(size_t)(k0 + (t >> 4)) * 256 + col0 + ((t & 15) << 2)];
        __syncthreads();
        #pragma unroll
        for (int kk = 0; kk < 16; ++kk) {
            float4 av = *(const float4*)&As[kk][tr << 2];
            float4 bv = *(const float4*)&Bs[kk][tc << 2];
            acc[0][0] += av.x * bv.x; acc[0][1] += av.x * bv.y;
            acc[0][2] += av.x * bv.z; acc[0][3] += av.x * bv.w;
            acc[1][0] += av.y * bv.x; acc[1][1] += av.y * bv.y;
            acc[1][2] += av.y * bv.z; acc[1][3] += av.y * bv.w;
            acc[2][0] += av.z * bv.x; acc[2][1] += av.z * bv.y;
            acc[2][2] += av.z * bv.z; acc[2][3] += av.z * bv.w;
            acc[3][0] += av.w * bv.x; acc[3][1] += av.w * bv.y;
            acc[3][2] += av.w * bv.z; acc[3][3] += av.w * bv.w;
        }
        __syncthreads();
    }

    float alpha = 1.f, beta = 0.f;
    if (skip) { alpha = 1.f / (1.f + __expf(-skip[0])); beta = 1.f - alpha; }
    const int col = col0 + (tc << 2);
    #pragma unroll
    for (int i = 0; i < 4; ++i) {
        int row = row0 + (tr << 2) + i;
        if (row >= nrows) break;
        float4 o;
        o.x = acc[i][0] + bias[col + 0];
        o.y = acc[i][1] + bias[col + 1];
        o.z = acc[i][2] + bias[col + 2];
        o.w = acc[i][3] + bias[col + 3];
        if (xres) {
            float4 xr = *(const float4*)&xres[(size_t)row * 256 + col];
            o.x = o.x * alpha + xr.x * beta;
            o.y = o.y * alpha + xr.y * beta;
            o.z = o.z * alpha + xr.z * beta;
            o.w = o.w * alpha + xr.w * beta;
        }
        *(float4*)&C[(size_t)row * 256 + col] = o;
    }
}

// ---------------------------------------------------------------------------
// Per-node head transform: out[n,h,f] = sum_d in[n,h,d] * A[h,d,f]
// A = rel_att[r] or rel_msg[r], 8x32x32 = 32KB staged in LDS.
// ---------------------------------------------------------------------------
__global__ void transform_kernel(const float* __restrict__ in, const float* __restrict__ A_g,
                                 float* __restrict__ out, int nnodes) {
    __shared__ float A[HH * DKK * DKK];  // 8192 floats = 32KB
    __shared__ float row[DD];
    for (int i = threadIdx.x; i < HH * DKK * DKK; i += 256) A[i] = A_g[i];
    __syncthreads();
    const int h = threadIdx.x >> 5, f = threadIdx.x & 31;
    const float* Ah = &A[h * 1024 + f];  // stride 32 over d
    const int base = blockIdx.x * NODES_PER_BLOCK;
    for (int ni = 0; ni < NODES_PER_BLOCK; ++ni) {
        const int n = base + ni;
        if (n >= nnodes) break;  // uniform across block
        row[threadIdx.x] = in[(size_t)n * 256 + threadIdx.x];
        __syncthreads();
        float s = 0.f;
        #pragma unroll
        for (int d = 0; d < DKK; ++d) s += row[h * 32 + d] * Ah[d * 32];
        out[(size_t)n * 256 + threadIdx.x] = s;
        __syncthreads();
    }
}

// ---------------------------------------------------------------------------
// Pass A: per edge, att[h] = dot(q[dst,h], kt[src,h]) * pri[h]/sqrt(dk);
// store exp(att), atomicAdd into den[dst,h]. (Max-pass skipped: att ~ N(0,1),
// exp can't overflow; softmax is shift-invariant.)
// ---------------------------------------------------------------------------
__global__ void edge_att_kernel(const float* __restrict__ q, const float* __restrict__ kt,
                                const int* __restrict__ src, const int* __restrict__ dst,
                                const float* __restrict__ pri, float* __restrict__ expatt,
                                float* __restrict__ den) {
    const int h = threadIdx.x >> 5, f = threadIdx.x & 31;
    for (int e = blockIdx.x; e < EE; e += gridDim.x) {
        const int s = src[e], d_ = dst[e];
        float p = q[(size_t)d_ * 256 + threadIdx.x] * kt[(size_t)s * 256 + threadIdx.x];
        #pragma unroll
        for (int off = 16; off; off >>= 1) p += __shfl_xor(p, off, 32);
        if (f == 0) {
            float a = expf(p * pri[h] * RSQRT_DK);
            expatt[(size_t)e * HH + h] = a;
            atomicAdd(&den[(size_t)d_ * HH + h], a);
        }
    }
}

// ---------------------------------------------------------------------------
// Pass B: t[dst] += 0.5 * (expatt/den[dst]) * vt[src]   (mean over R=2 fused)
// ---------------------------------------------------------------------------
__global__ void edge_agg_kernel(const float* __restrict__ vt, const int* __restrict__ src,
                                const int* __restrict__ dst, const float* __restrict__ expatt,
                                const float* __restrict__ den, float* __restrict__ t) {
    const int h = threadIdx.x >> 5;
    for (int e = blockIdx.x; e < EE; e += gridDim.x) {
        const int s = src[e], d_ = dst[e];
        const float w = 0.5f * expatt[(size_t)e * HH + h] / den[(size_t)d_ * HH + h];
        const float val = vt[(size_t)s * 256 + threadIdx.x];
        atomicAdd(&t[(size_t)d_ * 256 + threadIdx.x], w * val);
    }
}

// ---------------------------------------------------------------------------
extern "C" void kernel_launch(void* const* d_in, const int* in_sizes, int n_in,
                              void* d_out, int out_size, void* d_ws, size_t ws_size,
                              hipStream_t stream) {
    const float* x       = (const float*)d_in[0];
    const int*   src     = (const int*)d_in[1];
    const int*   dst     = (const int*)d_in[2];
    const float* Wk      = (const float*)d_in[3];
    const float* bk      = (const float*)d_in[4];
    const float* Wq      = (const float*)d_in[5];
    const float* bq      = (const float*)d_in[6];
    const float* Wv      = (const float*)d_in[7];
    const float* bv      = (const float*)d_in[8];
    const float* Wa      = (const float*)d_in[9];
    const float* ba      = (const float*)d_in[10];
    const float* rel_pri = (const float*)d_in[11];
    const float* rel_att = (const float*)d_in[12];
    const float* rel_msg = (const float*)d_in[13];
    const float* skip    = (const float*)d_in[14];
    float* out = (float*)d_out;
    float* ws  = (float*)d_ws;

    const size_t ND = (size_t)NN * DD;
    float* q      = ws;
    float* k      = ws + ND;
    float* v      = ws + 2 * ND;
    float* tb     = ws + 3 * ND;       // shared kt_r / vt_r buffer
    float* tt     = ws + 4 * ND;       // aggregated t [N,D]
    float* expatt = ws + 5 * ND;       // [E,H]
    float* den    = expatt + (size_t)EE * HH;  // [N,H]
    const size_t need = (5 * ND + (size_t)EE * HH + (size_t)NN * HH) * sizeof(float);
    if (ws_size < need) return;  // workspace too small -> visible correctness failure

    dim3 gg((NN + 63) / 64, DD / 64);
    sgemm_kernel<<<gg, 256, 0, stream>>>(x, Wq, bq, q, NN, nullptr, nullptr);
    sgemm_kernel<<<gg, 256, 0, stream>>>(x, Wk, bk, k, NN, nullptr, nullptr);
    sgemm_kernel<<<gg, 256, 0, stream>>>(x, Wv, bv, v, NN, nullptr, nullptr);
    hipMemsetAsync(tt, 0, ND * sizeof(float), stream);

    const int tgrid = (NN + NODES_PER_BLOCK - 1) / NODES_PER_BLOCK;
    for (int r = 0; r < 2; ++r) {
        transform_kernel<<<tgrid, 256, 0, stream>>>(k, rel_att + (size_t)r * HH * DKK * DKK, tb, NN);
        hipMemsetAsync(den, 0, (size_t)NN * HH * sizeof(float), stream);
        edge_att_kernel<<<EE, 256, 0, stream>>>(q, tb, src + (size_t)r * EE, dst + (size_t)r * EE,
                                                rel_pri + (size_t)r * HH, expatt, den);
        transform_kernel<<<tgrid, 256, 0, stream>>>(v, rel_msg + (size_t)r * HH * DKK * DKK, tb, NN);
        edge_agg_kernel<<<EE, 256, 0, stream>>>(tb, src + (size_t)r * EE, dst + (size_t)r * EE,
                                                expatt, den, tt);
    }
    sgemm_kernel<<<gg, 256, 0, stream>>>(tt, Wa, ba, out, NN, x, skip);
}